// Round 1
// baseline (262.289 us; speedup 1.0000x reference)
//
#include <hip/hip_runtime.h>
#include <hip/hip_bf16.h>

typedef __attribute__((ext_vector_type(8))) short bf16x8;
typedef __attribute__((ext_vector_type(4))) short bf16x4;
typedef __attribute__((ext_vector_type(4))) float f32x4;
typedef unsigned short u16;
typedef unsigned int u32;

#define NH 16
#define NKV 4
#define HD 64
#define BB 2
#define SS 2048
#define DD 1024
#define QKVD 1536   // (16 + 2*4) * 64

__device__ __forceinline__ u16 f2b(float f){
  __hip_bfloat16 h = __float2bfloat16(f);
  u16 u; __builtin_memcpy(&u, &h, 2); return u;
}

__device__ __forceinline__ void gload16(const void* g, void* l){
  __builtin_amdgcn_global_load_lds((const __attribute__((address_space(1))) void*)g,
                                   (__attribute__((address_space(3))) void*)l, 16, 0, 0);
}

__device__ __forceinline__ f32x4 mfma16(bf16x4 a, bf16x4 b, f32x4 c){
#if __has_builtin(__builtin_amdgcn_mfma_f32_16x16x16bf16_1k)
  return __builtin_amdgcn_mfma_f32_16x16x16bf16_1k(a, b, c, 0, 0, 0);
#else
  asm volatile("v_mfma_f32_16x16x16_bf16 %0, %1, %2, %0" : "+v"(c) : "v"(a), "v"(b));
  return c;
#endif
}

// ---------------- cast f32 -> bf16 (same layout), 4 elems/thread ----------------
__global__ __launch_bounds__(256) void cvt_bf16(const float* __restrict__ in,
                                                u16* __restrict__ out){
  int idx = (blockIdx.x * 256 + threadIdx.x) * 4;
  float4 v = *(const float4*)(in + idx);
  u32 lo = (u32)f2b(v.x) | ((u32)f2b(v.y) << 16);
  u32 hi = (u32)f2b(v.z) | ((u32)f2b(v.w) << 16);
  *(uint2*)(out + idx) = make_uint2(lo, hi);
}

// ------------- transpose + cast: in[K][N] f32 -> out[N][K] bf16 -----------------
__global__ __launch_bounds__(256) void transpose_cvt(const float* __restrict__ in,
                                                     u16* __restrict__ outT,
                                                     int K, int N){
  __shared__ u16 tile[64][65];
  int n0 = blockIdx.x * 64, k0 = blockIdx.y * 64;
  int cr = threadIdx.x >> 6;      // 0..3
  int cc = threadIdx.x & 63;
#pragma unroll
  for (int rr = 0; rr < 16; rr++){
    int row = rr * 4 + cr;        // k
    tile[row][cc] = f2b(in[(size_t)(k0 + row) * N + n0 + cc]);
  }
  __syncthreads();
#pragma unroll
  for (int rr = 0; rr < 16; rr++){
    int row = rr * 4 + cr;        // n
    outT[(size_t)(n0 + row) * K + k0 + cc] = tile[cc][row];
  }
}

// ---------------- bf16 GEMM: C[M][N] (f32) = A[M][K] * BT[N][K]^T ----------------
// m97 structure: 128x128 tile, BK=32, 4 waves (2x2), global_load_lds width 16.
__global__ __launch_bounds__(256) void gemm_bf16(const __hip_bfloat16* __restrict__ A,
                                                 const __hip_bfloat16* __restrict__ BT,
                                                 float* __restrict__ C,
                                                 int M, int N, int K){
  __shared__ __hip_bfloat16 As[128 * 32];
  __shared__ __hip_bfloat16 Bs[128 * 32];
  const int ntn = N >> 7;
  const int tm = blockIdx.x / ntn, tn = blockIdx.x % ntn;
  const int m0 = tm << 7, n0 = tn << 7;
  const int lane = threadIdx.x & 63, w = threadIdx.x >> 6;
  const int g = lane >> 4, i = lane & 15;
  const int wr = w >> 1, wc = w & 1;
  f32x4 acc[4][4] = {};
  const int srow = lane >> 2;          // 0..15 row in 16-row chunk
  const int scol = (lane & 3) * 8;     // k elem offset
  const __hip_bfloat16* ga = A  + (size_t)(m0 + w * 32 + srow) * K + scol;
  const __hip_bfloat16* gb = BT + (size_t)(n0 + w * 32 + srow) * K + scol;
  char* la = (char*)As + w * 2048;
  char* lb = (char*)Bs + w * 2048;
  for (int kt = 0; kt < K; kt += 32){
    gload16(ga, la); gload16(ga + (size_t)16 * K, la + 1024);
    gload16(gb, lb); gload16(gb + (size_t)16 * K, lb + 1024);
    ga += 32; gb += 32;
    asm volatile("s_waitcnt vmcnt(0)");
    __syncthreads();
    bf16x8 af[4], bfr[4];
#pragma unroll
    for (int x = 0; x < 4; x++){
      af[x]  = *(const bf16x8*)((const char*)As + (((wr * 64 + x * 16 + i) * 32) + g * 8) * 2);
      bfr[x] = *(const bf16x8*)((const char*)Bs + (((wc * 64 + x * 16 + i) * 32) + g * 8) * 2);
    }
#pragma unroll
    for (int mi = 0; mi < 4; mi++)
#pragma unroll
      for (int ni = 0; ni < 4; ni++)
        acc[mi][ni] = __builtin_amdgcn_mfma_f32_16x16x32_bf16(af[mi], bfr[ni], acc[mi][ni], 0, 0, 0);
    __syncthreads();
  }
  // D layout: col = lane&15, row = (lane>>4)*4 + reg
#pragma unroll
  for (int mi = 0; mi < 4; mi++)
#pragma unroll
    for (int ni = 0; ni < 4; ni++){
      size_t base = (size_t)(m0 + wr * 64 + mi * 16 + g * 4) * N + n0 + wc * 64 + ni * 16 + i;
#pragma unroll
      for (int r = 0; r < 4; r++)
        C[base + (size_t)r * N] = acc[mi][ni][r];
    }
}

// --------- RoPE + split: qkv[B*S][1536] f32 -> Q[b][h][s][64], K/V[b][kv][s][64] bf16
__global__ __launch_bounds__(256) void rope_split(const float* __restrict__ qkv,
                                                  const int* __restrict__ posp,
                                                  u16* __restrict__ Qr,
                                                  u16* __restrict__ Kr,
                                                  u16* __restrict__ Vb){
  int t = blockIdx.x * 256 + threadIdx.x;   // si*32 + p
  int p = t & 31, si = t >> 5;
  int h24 = blockIdx.y, bi = blockIdx.z;
  int kvh = h24 / 6, slot = h24 - kvh * 6;  // 0..3 q, 4 k, 5 v
  const float* src = qkv + (size_t)(bi * SS + si) * QKVD + h24 * 64 + 2 * p;
  float2 xv = *(const float2*)src;
  float o1, o2;
  u16* dst;
  if (slot == 5){
    o1 = xv.x; o2 = xv.y;
    dst = Vb + ((size_t)(bi * NKV + kvh) * SS + si) * 64 + 2 * p;
  } else {
    int pos0 = posp[0];
    float inv_freq = powf(10000.f, -(float)p * (1.f / 32.f));
    float ang = (float)(si + pos0) * inv_freq;
    float sn, cs;
    sincosf(ang, &sn, &cs);
    o1 = xv.x * cs - xv.y * sn;
    o2 = xv.x * sn + xv.y * cs;
    if (slot == 4){
      dst = Kr + ((size_t)(bi * NKV + kvh) * SS + si) * 64 + 2 * p;
    } else {
      o1 *= 0.125f; o2 *= 0.125f;   // fold 1/sqrt(hd) into q
      dst = Qr + ((size_t)(bi * NH + kvh * 4 + slot) * SS + si) * 64 + 2 * p;
    }
  }
  *(u32*)dst = (u32)f2b(o1) | ((u32)f2b(o2) << 16);
}

// ---------------- flash attention, causal, GQA ----------------
// Block = (b, h, q-tile of 64). 4 waves, each owns 16 q-rows.
// Swapped QK^T: ST = mfma(K, Q) -> lane(g,i) holds P^T[j = jb*16+4g+r][qrow i].
// PV via 16x16x16 mfma: A-frag k = 4g+jj lives in the SAME lane/regs -> no shuffle.
__global__ __launch_bounds__(256) void attn_fwd(const __hip_bfloat16* __restrict__ Qr,
                                                const __hip_bfloat16* __restrict__ Kr,
                                                const __hip_bfloat16* __restrict__ Vb,
                                                u16* __restrict__ Ao){
  const int blk = blockIdx.x;
  const int qt = blk & 31;
  const int hi = (blk >> 5) & 15;
  const int bi = blk >> 9;
  const int kvh = hi >> 2;
  const int lane = threadIdx.x & 63, w = threadIdx.x >> 6;
  const int g = lane >> 4, i = lane & 15;
  const int q0 = qt * 64 + w * 16;
  const u16* Qp = (const u16*)Qr + (size_t)(bi * NH + hi) * SS * 64;
  const u16* Kp = (const u16*)Kr + (size_t)(bi * NKV + kvh) * SS * 64;
  const u16* Vu = (const u16*)Vb + (size_t)(bi * NKV + kvh) * SS * 64;
  bf16x8 qf0 = *(const bf16x8*)(Qp + (size_t)(q0 + i) * 64 + g * 8);
  bf16x8 qf1 = *(const bf16x8*)(Qp + (size_t)(q0 + i) * 64 + 32 + g * 8);
  float m_row = -3.0e38f, l_row = 0.f;
  f32x4 o[4] = {};
  const int wlim = w * 16 + i;            // max valid j_rel in diagonal tile
  for (int kt = 0; kt <= qt; kt++){
    const int j0 = kt * 64;
    const bool diag = (kt == qt);
    f32x4 st[4];
#pragma unroll
    for (int jb = 0; jb < 4; jb++){
      const u16* kp = Kp + (size_t)(j0 + jb * 16 + i) * 64 + g * 8;
      bf16x8 kf0 = *(const bf16x8*)kp;
      bf16x8 kf1 = *(const bf16x8*)(kp + 32);
      f32x4 a = {};
      a = __builtin_amdgcn_mfma_f32_16x16x32_bf16(kf0, qf0, a, 0, 0, 0);
      a = __builtin_amdgcn_mfma_f32_16x16x32_bf16(kf1, qf1, a, 0, 0, 0);
      st[jb] = a;
    }
    float p[4][4];
    float pmax = -3.0e38f;
#pragma unroll
    for (int jb = 0; jb < 4; jb++)
#pragma unroll
      for (int r = 0; r < 4; r++){
        float v = st[jb][r];
        if (diag && (jb * 16 + g * 4 + r > wlim)) v = -3.0e38f;
        p[jb][r] = v;
        pmax = fmaxf(pmax, v);
      }
    pmax = fmaxf(pmax, __shfl_xor(pmax, 16, 64));
    pmax = fmaxf(pmax, __shfl_xor(pmax, 32, 64));
    const float mnew = fmaxf(m_row, pmax);
    const float alpha = __expf(m_row - mnew);
    float lsum = 0.f;
#pragma unroll
    for (int jb = 0; jb < 4; jb++)
#pragma unroll
      for (int r = 0; r < 4; r++){
        float e = __expf(p[jb][r] - mnew);
        p[jb][r] = e;
        lsum += e;
      }
    lsum += __shfl_xor(lsum, 16, 64);
    lsum += __shfl_xor(lsum, 32, 64);
    l_row = l_row * alpha + lsum;
    m_row = mnew;
    // rescale O: O rows are 4g+r -> fetch alpha from lane (4g+r)
    float a4[4];
#pragma unroll
    for (int r = 0; r < 4; r++) a4[r] = __shfl(alpha, g * 4 + r, 64);
#pragma unroll
    for (int db = 0; db < 4; db++){
#pragma unroll
      for (int r = 0; r < 4; r++) o[db][r] *= a4[r];
    }
    // PV: 16x16x16, A = P (k = 4g+jj, same lane/regs as ST output)
#pragma unroll
    for (int mk = 0; mk < 4; mk++){
      bf16x4 pa;
#pragma unroll
      for (int r = 0; r < 4; r++) pa[r] = (short)f2b(p[mk][r]);
      const size_t vbase = (size_t)(j0 + mk * 16 + g * 4) * 64 + i;
#pragma unroll
      for (int db = 0; db < 4; db++){
        bf16x4 vf;
#pragma unroll
        for (int jj = 0; jj < 4; jj++)
          vf[jj] = (short)Vu[vbase + (size_t)jj * 64 + db * 16];
        o[db] = mfma16(pa, vf, o[db]);
      }
    }
  }
  float linv[4];
#pragma unroll
  for (int r = 0; r < 4; r++) linv[r] = 1.f / __shfl(l_row, g * 4 + r, 64);
  const size_t obase = ((size_t)(bi * SS) + q0 + g * 4) * (NH * HD) + hi * 64 + i;
#pragma unroll
  for (int db = 0; db < 4; db++)
#pragma unroll
    for (int r = 0; r < 4; r++)
      Ao[obase + (size_t)r * (NH * HD) + db * 16] = f2b(o[db][r] * linv[r]);
}

extern "C" void kernel_launch(void* const* d_in, const int* in_sizes, int n_in,
                              void* d_out, int out_size, void* d_ws, size_t ws_size,
                              hipStream_t stream){
  const float* x    = (const float*)d_in[0];   // [2][2048][1024]
  const float* Wqkv = (const float*)d_in[1];   // [1024][1536]
  const float* Wo   = (const float*)d_in[2];   // [1024][1024]
  const int*   pos  = (const int*)d_in[3];
  float* out = (float*)d_out;                  // [2][2048][1024] f32
  char* ws = (char*)d_ws;

  // workspace layout (bytes)
  __hip_bfloat16* Xb    = (__hip_bfloat16*)(ws);             //  8 MiB  [4096][1024] bf16
  __hip_bfloat16* WqkvT = (__hip_bfloat16*)(ws + 8388608);   //  3 MiB  [1536][1024] bf16
  __hip_bfloat16* WoT   = (__hip_bfloat16*)(ws + 11534336);  //  2 MiB  [1024][1024] bf16
  float*          QKV   = (float*)(ws + 13631488);           // 24 MiB  [4096][1536] f32
  __hip_bfloat16* Qr    = (__hip_bfloat16*)(ws + 38797312);  //  8 MiB  [2][16][2048][64]
  __hip_bfloat16* Kr    = (__hip_bfloat16*)(ws + 47185920);  //  2 MiB  [2][4][2048][64]
  __hip_bfloat16* Vbuf  = (__hip_bfloat16*)(ws + 49283072);  //  2 MiB  [2][4][2048][64]
  __hip_bfloat16* Ao    = (__hip_bfloat16*)(ws);             // alias Xb (dead after GEMM1)

  cvt_bf16<<<4096, 256, 0, stream>>>(x, (u16*)Xb);                       // 4.19M elems
  transpose_cvt<<<dim3(24, 16), 256, 0, stream>>>(Wqkv, (u16*)WqkvT, 1024, 1536);
  transpose_cvt<<<dim3(16, 16), 256, 0, stream>>>(Wo,   (u16*)WoT,   1024, 1024);
  gemm_bf16<<<(4096/128)*(1536/128), 256, 0, stream>>>(Xb, WqkvT, QKV, 4096, 1536, 1024);
  rope_split<<<dim3(256, 24, 2), 256, 0, stream>>>(QKV, pos, (u16*)Qr, (u16*)Kr, (u16*)Vbuf);
  attn_fwd<<<BB * NH * (SS / 64), 256, 0, stream>>>(Qr, Kr, Vbuf, (u16*)Ao);
  gemm_bf16<<<(4096/128)*(1024/128), 256, 0, stream>>>(Ao, WoT, out, 4096, 1024, 1024);
}